// Round 1
// baseline (752.368 us; speedup 1.0000x reference)
//
#include <hip/hip_runtime.h>
#include <hip/hip_bf16.h>

// Problem: B=1024, S=64, E=256, H=512, V=128, C=32
#define BB 1024
#define SS 64
#define EE 256
#define HH 512
#define VV 128
#define CC 32

typedef _Float16 f16;
typedef _Float16 f16x8 __attribute__((ext_vector_type(8)));
typedef float    f32x4 __attribute__((ext_vector_type(4)));

#define ROWS   16   // batch rows per group
#define SLICES 4    // blocks per group (each owns 128 h-cols)
#define NCOLS  128  // h-cols per block
#define GROUPS 64   // 1024/16
#define HSTR   520  // h-buffer LDS stride in f16: 1040 B (16B-aligned, +4-bank skew)
#define PSTR   132  // P-tile LDS stride in floats (+4-bank skew)

// ---------------------------------------------------------------------------
// P[v][h] = emb[v,:] . W_ih[h,:] + b_ih[h] + b_hh[h]   (the whole input GEMM
// collapses to this 128x512 table since there are only V=128 tokens)
// ---------------------------------------------------------------------------
__global__ __launch_bounds__(256) void prep_P(
    const float* __restrict__ emb, const float* __restrict__ W_ih,
    const float* __restrict__ b_ih, const float* __restrict__ b_hh,
    float* __restrict__ P)
{
    __shared__ float er[EE];
    const int v = blockIdx.x;
    for (int i = threadIdx.x; i < EE; i += 256) er[i] = emb[(size_t)v * EE + i];
    __syncthreads();
    for (int h = threadIdx.x; h < HH; h += 256) {
        const float4* wr = (const float4*)(W_ih + (size_t)h * EE);
        float s = 0.f;
        #pragma unroll 4
        for (int e4 = 0; e4 < EE / 4; ++e4) {
            float4 w = wr[e4];
            const float* e = er + e4 * 4;
            s += w.x * e[0] + w.y * e[1] + w.z * e[2] + w.w * e[3];
        }
        P[(size_t)v * HH + h] = s + b_ih[h] + b_hh[h];
    }
}

// ---------------------------------------------------------------------------
// RNN: group g = 4 blocks {slice 0..3}, rows [16g,16g+16), block owns cols
// [128*slice, ...+128). W_hh slice lives in registers (bfr: 128 VGPR/lane).
// h_t lives in LDS (all 512 cols, assembled from the 4 slices each step via
// a global exchange buffer + agent-scope flags).
// ---------------------------------------------------------------------------
__global__ __launch_bounds__(256, 1) void rnn_kernel(
    const int* __restrict__ x_in, const int* __restrict__ x_lens,
    const float* __restrict__ W_hh, const float* __restrict__ P,
    f16* __restrict__ ex, int* __restrict__ flags, f16* __restrict__ last)
{
    __shared__ __align__(16) f16   hbuf[ROWS * HSTR];   // h_t, all 512 cols
    __shared__ __align__(16) float ptile[ROWS * PSTR];  // P rows for step t
    __shared__ int xin[ROWS * SS];
    __shared__ int lens[ROWS];

    const int tid   = threadIdx.x;
    const int blk   = blockIdx.x;
    const int g     = blk & 63;   // members {g, g+64, g+128, g+192}: same XCD
    const int slice = blk >> 6;   // under %8 round-robin (perf heuristic only)
    const int r0    = g * ROWS;
    const int n0    = slice * NCOLS;
    const int wave  = tid >> 6;
    const int lane  = tid & 63;
    const int lrow  = lane & 15;  // A row / B col / C col
    const int quad  = lane >> 4;

    // ---- one-time: W_hh slice -> B fragments in registers (f32->f16) ----
    // B[k][n] = W_hh[n][k]; lane layout: n = lane&15, k = quad*8 + j
    f16x8 bfr[2][16];
    {
        const int nbase = n0 + wave * 32 + lrow;
        #pragma unroll
        for (int tile = 0; tile < 2; ++tile) {
            const float* wr = W_hh + (size_t)(nbase + tile * 16) * HH + quad * 8;
            #pragma unroll
            for (int K0 = 0; K0 < 16; ++K0) {
                float4 x0 = *(const float4*)(wr + K0 * 32);
                float4 x1 = *(const float4*)(wr + K0 * 32 + 4);
                f16x8 b;
                b[0] = (f16)x0.x; b[1] = (f16)x0.y; b[2] = (f16)x0.z; b[3] = (f16)x0.w;
                b[4] = (f16)x1.x; b[5] = (f16)x1.y; b[6] = (f16)x1.z; b[7] = (f16)x1.w;
                bfr[tile][K0] = b;
            }
        }
    }

    // ---- LDS init: h_0 = 0, token tile, lengths ----
    for (int i = tid; i < ROWS * HSTR; i += 256) hbuf[i] = (f16)0.f;
    // rows r0..r0+15 of x_in are contiguous: flat int4 copy (256 chunks)
    for (int i = tid; i < ROWS * (SS / 4); i += 256)
        ((int4*)xin)[i] = ((const int4*)(x_in + (size_t)r0 * SS))[i];
    if (tid < ROWS) lens[tid] = x_lens[r0 + tid];
    __syncthreads();

    // P prefetch mapping: thread -> (row, 8-col chunk)
    const int pr_ = tid >> 4;
    const int pc_ = (tid & 15) << 3;
    float4 pf0, pf1;
    {
        const int tok = xin[pr_ * SS + 0];
        const float4* p4 = (const float4*)(P + (size_t)tok * HH + n0 + pc_);
        pf0 = p4[0]; pf1 = p4[1];
    }

    int* myflag = &flags[g * SLICES + slice];

    for (int t = 0; t < SS; ++t) {
        // stage current P tile (written last step's prefetch), prefetch next
        *(float4*)(ptile + pr_ * PSTR + pc_)     = pf0;
        *(float4*)(ptile + pr_ * PSTR + pc_ + 4) = pf1;
        if (t + 1 < SS) {
            const int tok = xin[pr_ * SS + t + 1];
            const float4* p4 = (const float4*)(P + (size_t)tok * HH + n0 + pc_);
            pf0 = p4[0]; pf1 = p4[1];
        }

        // ---- MFMA: [16 rows] x [32 cols per wave], K=512 ----
        f32x4 acc0 = {0.f, 0.f, 0.f, 0.f}, acc1 = {0.f, 0.f, 0.f, 0.f};
        const f16* arow = hbuf + lrow * HSTR + quad * 8;
        #pragma unroll
        for (int K0 = 0; K0 < 16; ++K0) {
            f16x8 a = *(const f16x8*)(arow + K0 * 32);
            acc0 = __builtin_amdgcn_mfma_f32_16x16x32_f16(a, bfr[0][K0], acc0, 0, 0, 0);
            acc1 = __builtin_amdgcn_mfma_f32_16x16x32_f16(a, bfr[1][K0], acc1, 0, 0, 0);
        }

        __syncthreads();  // all waves done reading h_t; ptile visible

        // ---- epilogue: h_{t+1} own slice; C layout col=lane&15, row=quad*4+r
        const int slot = t & 1;
        f16* exw = ex + (((size_t)slot * GROUPS + g) * SLICES + slice) * (ROWS * NCOLS);
        const int tp1 = t + 1;
        #pragma unroll
        for (int tile = 0; tile < 2; ++tile) {
            const int cloc = wave * 32 + tile * 16 + lrow;
            f32x4 acc = tile ? acc1 : acc0;
            #pragma unroll
            for (int r = 0; r < 4; ++r) {
                const int row = quad * 4 + r;
                float hv = tanhf(acc[r] + ptile[row * PSTR + cloc]);
                f16 h16 = (f16)hv;
                hbuf[row * HSTR + n0 + cloc] = h16;   // own cols for next step
                exw[row * NCOLS + cloc] = h16;        // publish to peers
                if (lens[row] == tp1)                 // gather at x_lens-1
                    last[(size_t)(r0 + row) * HH + n0 + cloc] = h16;
            }
        }

        if (t == SS - 1) break;

        // ---- publish + sync with the 3 peer slices ----
        __syncthreads();  // drains vmcnt(0): all waves' ex stores are in L2
        if (tid == 0)     // release: L2 writeback so other XCDs can see data
            __hip_atomic_store(myflag, tp1, __ATOMIC_RELEASE, __HIP_MEMORY_SCOPE_AGENT);
        if (tid < SLICES - 1) {
            const int p = tid + (tid >= slice ? 1 : 0);
            while (__hip_atomic_load(&flags[g * SLICES + p], __ATOMIC_ACQUIRE,
                                     __HIP_MEMORY_SCOPE_AGENT) < tp1)
                __builtin_amdgcn_s_sleep(1);
        }
        __syncthreads();

        // ---- pull peer slices into hbuf (3*16*128 f16 = 3072 dwords) ----
        const unsigned* exr =
            (const unsigned*)(ex + ((size_t)slot * GROUPS + g) * SLICES * (ROWS * NCOLS));
        #pragma unroll
        for (int i = 0; i < 12; ++i) {
            const int idx = tid + i * 256;
            const int p   = idx >> 10;
            const int rem = idx & 1023;
            const int row = rem >> 6;
            const int cd  = rem & 63;
            const int pg  = p + (p >= slice ? 1 : 0);
            unsigned v = exr[(pg * ROWS + row) * (NCOLS / 2) + cd];
            *(unsigned*)(hbuf + row * HSTR + pg * NCOLS + cd * 2) = v;
        }
        __syncthreads();
    }
}

// ---------------------------------------------------------------------------
// MLP layer 1 via MFMA: hidden = relu(last @ W1^T + b1). Same tiling as the
// RNN step, single pass, no exchange.
// ---------------------------------------------------------------------------
__global__ __launch_bounds__(256, 1) void mlp1_kernel(
    const f16* __restrict__ last, const float* __restrict__ W1,
    const float* __restrict__ b1, f16* __restrict__ hidden)
{
    __shared__ __align__(16) f16 hb[ROWS * HSTR];
    const int tid   = threadIdx.x;
    const int g     = blockIdx.x & 63;
    const int slice = blockIdx.x >> 6;
    const int r0    = g * ROWS;
    const int n0    = slice * NCOLS;
    const int wave  = tid >> 6;
    const int lane  = tid & 63;
    const int lrow  = lane & 15;
    const int quad  = lane >> 4;

    f16x8 bfr[2][16];
    {
        const int nbase = n0 + wave * 32 + lrow;
        #pragma unroll
        for (int tile = 0; tile < 2; ++tile) {
            const float* wr = W1 + (size_t)(nbase + tile * 16) * HH + quad * 8;
            #pragma unroll
            for (int K0 = 0; K0 < 16; ++K0) {
                float4 x0 = *(const float4*)(wr + K0 * 32);
                float4 x1 = *(const float4*)(wr + K0 * 32 + 4);
                f16x8 b;
                b[0] = (f16)x0.x; b[1] = (f16)x0.y; b[2] = (f16)x0.z; b[3] = (f16)x0.w;
                b[4] = (f16)x1.x; b[5] = (f16)x1.y; b[6] = (f16)x1.z; b[7] = (f16)x1.w;
                bfr[tile][K0] = b;
            }
        }
    }

    // stage 16 'last' rows (f16, 16B chunks)
    for (int i = tid; i < ROWS * (HH / 8); i += 256) {
        const int row = i >> 6;
        const int c8  = (i & 63) * 8;
        *(float4*)(hb + row * HSTR + c8) =
            *(const float4*)(last + (size_t)(r0 + row) * HH + c8);
    }
    __syncthreads();

    f32x4 acc0 = {0.f, 0.f, 0.f, 0.f}, acc1 = {0.f, 0.f, 0.f, 0.f};
    const f16* arow = hb + lrow * HSTR + quad * 8;
    #pragma unroll
    for (int K0 = 0; K0 < 16; ++K0) {
        f16x8 a = *(const f16x8*)(arow + K0 * 32);
        acc0 = __builtin_amdgcn_mfma_f32_16x16x32_f16(a, bfr[0][K0], acc0, 0, 0, 0);
        acc1 = __builtin_amdgcn_mfma_f32_16x16x32_f16(a, bfr[1][K0], acc1, 0, 0, 0);
    }
    #pragma unroll
    for (int tile = 0; tile < 2; ++tile) {
        const int cloc = wave * 32 + tile * 16 + lrow;
        f32x4 acc = tile ? acc1 : acc0;
        const float bb = b1[n0 + cloc];
        #pragma unroll
        for (int r = 0; r < 4; ++r) {
            const int row = quad * 4 + r;
            hidden[(size_t)(r0 + row) * HH + n0 + cloc] =
                (f16)fmaxf(acc[r] + bb, 0.f);
        }
    }
}

// ---------------------------------------------------------------------------
// logits = hidden @ W2^T + b2  (1024x32, K=512) — small, fp32 VALU
// ---------------------------------------------------------------------------
__global__ __launch_bounds__(256) void mlp2_kernel(
    const f16* __restrict__ hidden, const float* __restrict__ W2,
    const float* __restrict__ b2, float* __restrict__ out)
{
    __shared__ float hs[8][512];
    const int b0 = blockIdx.x * 8;
    for (int i = threadIdx.x; i < 8 * 512; i += 256)
        hs[i >> 9][i & 511] = (float)hidden[(size_t)(b0 + (i >> 9)) * HH + (i & 511)];
    __syncthreads();
    const int r = threadIdx.x >> 5, c = threadIdx.x & 31;
    const float4* w = (const float4*)(W2 + (size_t)c * HH);
    float acc = 0.f;
    #pragma unroll 4
    for (int k4 = 0; k4 < 128; ++k4) {
        float4 wv = w[k4];
        float4 hv = *(const float4*)(&hs[r][k4 * 4]);
        acc += wv.x * hv.x + wv.y * hv.y + wv.z * hv.z + wv.w * hv.w;
    }
    out[(size_t)(b0 + r) * CC + c] = acc + b2[c];
}

// ---------------------------------------------------------------------------
extern "C" void kernel_launch(void* const* d_in, const int* in_sizes, int n_in,
                              void* d_out, int out_size, void* d_ws, size_t ws_size,
                              hipStream_t stream)
{
    const int*   x_in   = (const int*)d_in[0];
    const int*   x_lens = (const int*)d_in[1];
    const float* emb    = (const float*)d_in[2];
    const float* W_ih   = (const float*)d_in[3];
    const float* b_ih   = (const float*)d_in[4];
    const float* W_hh   = (const float*)d_in[5];
    const float* b_hh   = (const float*)d_in[6];
    const float* W1     = (const float*)d_in[7];
    const float* b1     = (const float*)d_in[8];
    const float* W2     = (const float*)d_in[9];
    const float* b2     = (const float*)d_in[10];
    float* out = (float*)d_out;

    // workspace carve (re-poisoned every launch; everything rewritten below)
    char* ws = (char*)d_ws;
    float* P      = (float*)ws;                                  // 256 KiB
    f16*   ex     = (f16*)(ws + (256 << 10));                    // 2 MiB
    int*   flags  = (int*)(ws + (256 << 10) + (2 << 20));        // 1 KiB
    f16*   last   = (f16*)(ws + (256 << 10) + (2 << 20) + 1024); // 1 MiB
    f16*   hidden = (f16*)(ws + (256 << 10) + (2 << 20) + 1024 + (1 << 20)); // 1 MiB

    hipMemsetAsync(flags, 0, GROUPS * SLICES * sizeof(int), stream);
    hipLaunchKernelGGL(prep_P, dim3(VV), dim3(256), 0, stream,
                       emb, W_ih, b_ih, b_hh, P);
    hipLaunchKernelGGL(rnn_kernel, dim3(GROUPS * SLICES), dim3(256), 0, stream,
                       x_in, x_lens, W_hh, P, ex, flags, last);
    hipLaunchKernelGGL(mlp1_kernel, dim3(GROUPS * SLICES), dim3(256), 0, stream,
                       last, W1, b1, hidden);
    hipLaunchKernelGGL(mlp2_kernel, dim3(BB / 8), dim3(256), 0, stream,
                       hidden, W2, b2, out);
}

// Round 3
// 426.697 us; speedup vs baseline: 1.7632x; 1.7632x over previous
//
#include <hip/hip_runtime.h>
#include <hip/hip_bf16.h>

// Problem: B=1024, S=64, E=256, H=512, V=128, C=32
#define BB 1024
#define SS 64
#define EE 256
#define HH 512
#define VV 128
#define CC 32

typedef _Float16 f16;
typedef _Float16 f16x8 __attribute__((ext_vector_type(8)));
typedef float    f32x4 __attribute__((ext_vector_type(4)));

// ---------------------------------------------------------------------------
// P[v][h] = emb[v,:] . W_ih[h,:] + b_ih[h] + b_hh[h]  (f16 output table)
// ---------------------------------------------------------------------------
__global__ __launch_bounds__(256) void prep_P(
    const float* __restrict__ emb, const float* __restrict__ W_ih,
    const float* __restrict__ b_ih, const float* __restrict__ b_hh,
    f16* __restrict__ P)
{
    __shared__ float er[EE];
    const int v = blockIdx.x;
    for (int i = threadIdx.x; i < EE; i += 256) er[i] = emb[(size_t)v * EE + i];
    __syncthreads();
    for (int h = threadIdx.x; h < HH; h += 256) {
        const float4* wr = (const float4*)(W_ih + (size_t)h * EE);
        float s = 0.f;
        #pragma unroll 4
        for (int e4 = 0; e4 < EE / 4; ++e4) {
            float4 w = wr[e4];
            const float* e = er + e4 * 4;
            s += w.x * e[0] + w.y * e[1] + w.z * e[2] + w.w * e[3];
        }
        P[(size_t)v * HH + h] = (f16)(s + b_ih[h] + b_hh[h]);
    }
}

// ---------------------------------------------------------------------------
// RNN, zero inter-block communication. 64 blocks x 512 threads (8 waves).
// Block owns 16 batch rows and computes ALL 512 h-cols, so h never leaves
// the block. W_hh (512x512 f16 = 512 KB) per-CU: k 0..415 in registers
// (bfr[4][13] = 208 VGPR/lane across 8 waves = 416 KB), k 416..511 in
// STATIC LDS (96 KB; gfx950 allows 160 KB/workgroup — no dynamic opt-in).
// Wave w owns output cols [64w, 64w+64) = 4 MFMA N-tiles.
// ---------------------------------------------------------------------------
#define KSREG 13           // k-steps (of 32) held in registers
#define KSLDS 3            // k-steps held in LDS
#define HSTR  520          // hbuf stride in f16 (1040 B: 16B-aligned, +4-bank skew)
#define PSTRH 520          // ptile stride in f16

__global__ __launch_bounds__(512, 2) void rnn_kernel(
    const int* __restrict__ x_in, const int* __restrict__ x_lens,
    const float* __restrict__ W_hh, const f16* __restrict__ P,
    f16* __restrict__ last)
{
    __shared__ __align__(16) f16 hbuf[16 * HSTR];    // h_t, 16 rows x 512 cols
    __shared__ __align__(16) f16 ptile[16 * PSTRH];  // P rows for current step
    __shared__ __align__(16) f16 wlds[8 * 4 * KSLDS * 64 * 8];  // 96 KB W frags
    __shared__ int xin[16 * SS];
    __shared__ int lens[16];

    const int tid  = threadIdx.x;
    const int r0   = blockIdx.x * 16;
    const int wave = tid >> 6;       // 0..7 -> cols [64w, 64w+64)
    const int lane = tid & 63;
    const int lrow = lane & 15;      // A-row / B-col / C-col within tile
    const int quad = lane >> 4;
    const int n0w  = wave * 64;

    // ---- one-time: W_hh -> register fragments + LDS fragments (f32->f16) ----
    // B[k][n] = W_hh[n][k]; lane holds n = lrow (+16t+64w), k = 32ks + 8quad + j
    f16x8 bfr[4][KSREG];
    #pragma unroll
    for (int t = 0; t < 4; ++t) {
        const float* wr = W_hh + (size_t)(n0w + 16 * t + lrow) * HH + quad * 8;
        #pragma unroll
        for (int ks = 0; ks < KSREG; ++ks) {
            float4 x0 = *(const float4*)(wr + ks * 32);
            float4 x1 = *(const float4*)(wr + ks * 32 + 4);
            f16x8 b;
            b[0] = (f16)x0.x; b[1] = (f16)x0.y; b[2] = (f16)x0.z; b[3] = (f16)x0.w;
            b[4] = (f16)x1.x; b[5] = (f16)x1.y; b[6] = (f16)x1.z; b[7] = (f16)x1.w;
            bfr[t][ks] = b;
        }
        #pragma unroll
        for (int ks = 0; ks < KSLDS; ++ks) {
            float4 x0 = *(const float4*)(wr + (KSREG + ks) * 32);
            float4 x1 = *(const float4*)(wr + (KSREG + ks) * 32 + 4);
            f16x8 b;
            b[0] = (f16)x0.x; b[1] = (f16)x0.y; b[2] = (f16)x0.z; b[3] = (f16)x0.w;
            b[4] = (f16)x1.x; b[5] = (f16)x1.y; b[6] = (f16)x1.z; b[7] = (f16)x1.w;
            // swizzled: lane-consecutive 16B chunks, conflict-free b128 reads
            *(f16x8*)(wlds + ((((wave * 4 + t) * KSLDS + ks) * 64 + lane) << 3)) = b;
        }
    }

    // ---- LDS init: h_0 = 0, token tile, lengths ----
    for (int i = tid; i < 16 * HSTR; i += 512) hbuf[i] = (f16)0.f;
    for (int i = tid; i < 16 * (SS / 4); i += 512)
        ((int4*)xin)[i] = ((const int4*)(x_in + (size_t)r0 * SS))[i];
    if (tid < 16) lens[tid] = x_lens[r0 + tid];
    __syncthreads();

    // ptile staging map: thread -> (row, 16-f16 chunk)
    const int srow = tid >> 5;
    const int scol = (tid & 31) << 4;
    {   // stage ptile for step 0
        const int tok = xin[srow * SS + 0];
        const float4* p4 = (const float4*)(P + (size_t)tok * HH + scol);
        *(float4*)(ptile + srow * PSTRH + scol)     = p4[0];
        *(float4*)(ptile + srow * PSTRH + scol + 8) = p4[1];
    }
    __syncthreads();

    const f16* arow = hbuf + lrow * HSTR + quad * 8;

    for (int st = 0; st < SS; ++st) {
        // prefetch next step's P rows into registers (consumed after sync)
        float4 pf0, pf1;
        if (st + 1 < SS) {
            const int tok = xin[srow * SS + st + 1];
            const float4* p4 = (const float4*)(P + (size_t)tok * HH + scol);
            pf0 = p4[0]; pf1 = p4[1];
        }

        // ---- MFMA: 16 rows x 64 cols/wave, K = 512 ----
        f32x4 acc0 = {0,0,0,0}, acc1 = {0,0,0,0}, acc2 = {0,0,0,0}, acc3 = {0,0,0,0};
        #pragma unroll
        for (int ks = 0; ks < KSREG; ++ks) {
            f16x8 a = *(const f16x8*)(arow + ks * 32);
            acc0 = __builtin_amdgcn_mfma_f32_16x16x32_f16(a, bfr[0][ks], acc0, 0, 0, 0);
            acc1 = __builtin_amdgcn_mfma_f32_16x16x32_f16(a, bfr[1][ks], acc1, 0, 0, 0);
            acc2 = __builtin_amdgcn_mfma_f32_16x16x32_f16(a, bfr[2][ks], acc2, 0, 0, 0);
            acc3 = __builtin_amdgcn_mfma_f32_16x16x32_f16(a, bfr[3][ks], acc3, 0, 0, 0);
        }
        #pragma unroll
        for (int ks = 0; ks < KSLDS; ++ks) {
            f16x8 a = *(const f16x8*)(arow + (KSREG + ks) * 32);
            f16x8 b0 = *(const f16x8*)(wlds + ((((wave * 4 + 0) * KSLDS + ks) * 64 + lane) << 3));
            f16x8 b1 = *(const f16x8*)(wlds + ((((wave * 4 + 1) * KSLDS + ks) * 64 + lane) << 3));
            f16x8 b2 = *(const f16x8*)(wlds + ((((wave * 4 + 2) * KSLDS + ks) * 64 + lane) << 3));
            f16x8 b3 = *(const f16x8*)(wlds + ((((wave * 4 + 3) * KSLDS + ks) * 64 + lane) << 3));
            acc0 = __builtin_amdgcn_mfma_f32_16x16x32_f16(a, b0, acc0, 0, 0, 0);
            acc1 = __builtin_amdgcn_mfma_f32_16x16x32_f16(a, b1, acc1, 0, 0, 0);
            acc2 = __builtin_amdgcn_mfma_f32_16x16x32_f16(a, b2, acc2, 0, 0, 0);
            acc3 = __builtin_amdgcn_mfma_f32_16x16x32_f16(a, b3, acc3, 0, 0, 0);
        }

        __syncthreads();  // all waves done reading hbuf/ptile for this step

        // ---- epilogue: h_{st+1} = tanh(acc + P); C layout col=lrow, row=quad*4+r
        const int tp1 = st + 1;
        #pragma unroll
        for (int t = 0; t < 4; ++t) {
            const int col = n0w + 16 * t + lrow;
            const f32x4 acc = (t == 0) ? acc0 : (t == 1) ? acc1 : (t == 2) ? acc2 : acc3;
            #pragma unroll
            for (int r = 0; r < 4; ++r) {
                const int row = quad * 4 + r;
                float z = acc[r] + (float)ptile[row * PSTRH + col];
                // tanh(z) = 1 - 2/(e^{2z}+1); exp over/underflow saturate correctly
                float e = __expf(2.f * z);
                f16 h16 = (f16)(1.f - 2.f / (e + 1.f));
                hbuf[row * HSTR + col] = h16;
                if (lens[row] == tp1)
                    last[(size_t)(r0 + row) * HH + col] = h16;
            }
        }

        __syncthreads();  // epilogue done: safe to overwrite ptile, read new hbuf

        if (st + 1 < SS) {
            *(float4*)(ptile + srow * PSTRH + scol)     = pf0;
            *(float4*)(ptile + srow * PSTRH + scol + 8) = pf1;
        }
    }
}

// ---------------------------------------------------------------------------
// MLP layer 1 via MFMA: hidden = relu(last @ W1^T + b1). 256 blocks,
// block = (group g of 16 rows) x (slice of 128 cols).
// ---------------------------------------------------------------------------
__global__ __launch_bounds__(256, 1) void mlp1_kernel(
    const f16* __restrict__ last, const float* __restrict__ W1,
    const float* __restrict__ b1, f16* __restrict__ hidden)
{
    __shared__ __align__(16) f16 hb[16 * HSTR];
    const int tid   = threadIdx.x;
    const int g     = blockIdx.x & 63;
    const int slice = blockIdx.x >> 6;
    const int r0    = g * 16;
    const int n0    = slice * 128;
    const int wave  = tid >> 6;
    const int lane  = tid & 63;
    const int lrow  = lane & 15;
    const int quad  = lane >> 4;

    f16x8 bfr[2][16];
    {
        const int nbase = n0 + wave * 32 + lrow;
        #pragma unroll
        for (int tile = 0; tile < 2; ++tile) {
            const float* wr = W1 + (size_t)(nbase + tile * 16) * HH + quad * 8;
            #pragma unroll
            for (int K0 = 0; K0 < 16; ++K0) {
                float4 x0 = *(const float4*)(wr + K0 * 32);
                float4 x1 = *(const float4*)(wr + K0 * 32 + 4);
                f16x8 b;
                b[0] = (f16)x0.x; b[1] = (f16)x0.y; b[2] = (f16)x0.z; b[3] = (f16)x0.w;
                b[4] = (f16)x1.x; b[5] = (f16)x1.y; b[6] = (f16)x1.z; b[7] = (f16)x1.w;
                bfr[tile][K0] = b;
            }
        }
    }

    for (int i = tid; i < 16 * (HH / 8); i += 256) {
        const int row = i >> 6;
        const int c8  = (i & 63) * 8;
        *(float4*)(hb + row * HSTR + c8) =
            *(const float4*)(last + (size_t)(r0 + row) * HH + c8);
    }
    __syncthreads();

    f32x4 acc0 = {0,0,0,0}, acc1 = {0,0,0,0};
    const f16* arow = hb + lrow * HSTR + quad * 8;
    #pragma unroll
    for (int K0 = 0; K0 < 16; ++K0) {
        f16x8 a = *(const f16x8*)(arow + K0 * 32);
        acc0 = __builtin_amdgcn_mfma_f32_16x16x32_f16(a, bfr[0][K0], acc0, 0, 0, 0);
        acc1 = __builtin_amdgcn_mfma_f32_16x16x32_f16(a, bfr[1][K0], acc1, 0, 0, 0);
    }
    #pragma unroll
    for (int tile = 0; tile < 2; ++tile) {
        const int cloc = wave * 32 + tile * 16 + lrow;
        f32x4 acc = tile ? acc1 : acc0;
        const float bb = b1[n0 + cloc];
        #pragma unroll
        for (int r = 0; r < 4; ++r) {
            const int row = quad * 4 + r;
            hidden[(size_t)(r0 + row) * HH + n0 + cloc] =
                (f16)fmaxf(acc[r] + bb, 0.f);
        }
    }
}

// ---------------------------------------------------------------------------
// logits = hidden @ W2^T + b2  (1024x32, K=512) — small, fp32 VALU
// ---------------------------------------------------------------------------
__global__ __launch_bounds__(256) void mlp2_kernel(
    const f16* __restrict__ hidden, const float* __restrict__ W2,
    const float* __restrict__ b2, float* __restrict__ out)
{
    __shared__ float hs[8][512];
    const int b0 = blockIdx.x * 8;
    for (int i = threadIdx.x; i < 8 * 512; i += 256)
        hs[i >> 9][i & 511] = (float)hidden[(size_t)(b0 + (i >> 9)) * HH + (i & 511)];
    __syncthreads();
    const int r = threadIdx.x >> 5, c = threadIdx.x & 31;
    const float4* w = (const float4*)(W2 + (size_t)c * HH);
    float acc = 0.f;
    #pragma unroll 4
    for (int k4 = 0; k4 < 128; ++k4) {
        float4 wv = w[k4];
        float4 hv = *(const float4*)(&hs[r][k4 * 4]);
        acc += wv.x * hv.x + wv.y * hv.y + wv.z * hv.z + wv.w * hv.w;
    }
    out[(size_t)(b0 + r) * CC + c] = acc + b2[c];
}

// ---------------------------------------------------------------------------
extern "C" void kernel_launch(void* const* d_in, const int* in_sizes, int n_in,
                              void* d_out, int out_size, void* d_ws, size_t ws_size,
                              hipStream_t stream)
{
    const int*   x_in   = (const int*)d_in[0];
    const int*   x_lens = (const int*)d_in[1];
    const float* emb    = (const float*)d_in[2];
    const float* W_ih   = (const float*)d_in[3];
    const float* b_ih   = (const float*)d_in[4];
    const float* W_hh   = (const float*)d_in[5];
    const float* b_hh   = (const float*)d_in[6];
    const float* W1     = (const float*)d_in[7];
    const float* b1     = (const float*)d_in[8];
    const float* W2     = (const float*)d_in[9];
    const float* b2     = (const float*)d_in[10];
    float* out = (float*)d_out;

    // workspace carve (re-poisoned every launch; everything rewritten below)
    char* ws = (char*)d_ws;
    f16* P      = (f16*)ws;                             // 128 KiB (slot 256 KiB)
    f16* last   = (f16*)(ws + (256 << 10));             // 1 MiB
    f16* hidden = (f16*)(ws + (256 << 10) + (1 << 20)); // 1 MiB

    hipLaunchKernelGGL(prep_P, dim3(VV), dim3(256), 0, stream,
                       emb, W_ih, b_ih, b_hh, P);
    hipLaunchKernelGGL(rnn_kernel, dim3(BB / 16), dim3(512), 0, stream,
                       x_in, x_lens, W_hh, P, last);
    hipLaunchKernelGGL(mlp1_kernel, dim3(256), dim3(256), 0, stream,
                       last, W1, b1, hidden);
    hipLaunchKernelGGL(mlp2_kernel, dim3(BB / 8), dim3(256), 0, stream,
                       hidden, W2, b2, out);
}